// Round 5
// baseline (808.432 us; speedup 1.0000x reference)
//
#include <hip/hip_runtime.h>

// GNN_layer: N=4, A_IN=8, A_OUT=16, X=64, n=1024.
// Inputs: float32. Outputs: float32 (reference output dtype).
// Decomposition:
//   At[b,i,j,s] = Base + pairA[i,s] + pairA[j,s] + constA[s],  Base = sum_c A[b,c,i,j] W1[c,s]
//   einsum factors through G[b,c,i,t] = A[b,c] @ X2t (MFMA, A cast to bf16 in-reg).
// ROUND 5: fix round-4's VGPR regression. __launch_bounds__(1024, 4) made the compiler
// allocate 64 VGPR -> the 16-register A buffer spilled to scratch (FETCH 87->524 MB,
// WRITE 263->764 MB, 163->415 us). A 1024-thread block already implies a 128-VGPR cap
// (16 waves must co-reside at 4/SIMD), so plain __launch_bounds__(1024) gives the same
// 16 waves/CU with round-3's spill-free 128-VGPR codegen. Everything else identical to
// round 4 (16 waves = nt t-quarter x jq j-quarter, serial LDS G-reduction, fused epilogue).

#define NB 4
#define CI 8
#define SO 16
#define XD 64
#define NN 1024

typedef unsigned short u16;
typedef unsigned int u32;
typedef float f32x4 __attribute__((ext_vector_type(4)));
typedef short bf16x8 __attribute__((ext_vector_type(8)));

// ---- workspace layout (bytes), total <= 0x660000 = 6.7 MB ----
#define WS_MOC    0x000000u  // f32[4*8*1024]
#define WS_DP     0x020000u  // f32[4*8*1024]
#define WS_CONSTA 0x043000u  // f32[4*16]
#define WS_CX1    0x044000u  // f32[4*64]
#define WS_CX2    0x045000u  // f32[4*64]
#define WS_K1     0x048000u  // f32[4*16*64]
#define WS_C2     0x04C000u  // f32[4*64]
#define WS_PAIRA  0x050000u  // f32[4*1024*16]
#define WS_PAIRAT 0x090000u  // f32[4*16*1024]
#define WS_X1T    0x0D0000u  // f32[4*1024*64]
#define WS_X2TT   0x1D0000u  // bf16[4*64*1024]
#define WS_WGT    0x250000u  // bf16[64*512]
#define WS_H      0x260000u  // f32[4*16*64]   (16 KB)
#define WS_XPART  0x264000u  // f32[64*64]     (16 KB)
#define WS_S2     0x268000u  // f32[4*64]      (1 KB)

__device__ __forceinline__ float bf2f(u16 u){ return __uint_as_float(((u32)u) << 16); }
__device__ __forceinline__ u16 f2bf(float f){
    u32 x = __float_as_uint(f);
    x += 0x7fffu + ((x >> 16) & 1u);
    return (u16)(x >> 16);
}

// ---------------- K1: per-row stats of A (moc, dp) + X column-sum partials ----------------
__global__ __launch_bounds__(256) void k_rowstats(const float* __restrict__ A,
                                                  const float* __restrict__ X,
                                                  float* __restrict__ moc,
                                                  float* __restrict__ dpv,
                                                  float* __restrict__ Xpart)
{
    if (blockIdx.x < NB*CI*NN/4) {
        int wave = threadIdx.x >> 6, lane = threadIdx.x & 63;
        int row = blockIdx.x * 4 + wave;           // (b*8+c)*1024 + i
        int i = row & (NN - 1);
        const float* rp = A + (size_t)row * NN;
        f32x4 v0 = *(const f32x4*)(rp + lane * 16);
        f32x4 v1 = *(const f32x4*)(rp + lane * 16 + 4);
        f32x4 v2 = *(const f32x4*)(rp + lane * 16 + 8);
        f32x4 v3 = *(const f32x4*)(rp + lane * 16 + 12);
        float s = 0.f;
        #pragma unroll
        for (int e = 0; e < 4; e++) s += v0[e] + v1[e] + v2[e] + v3[e];
        #pragma unroll
        for (int off = 32; off; off >>= 1) s += __shfl_down(s, off);
        if (lane == 0) {
            moc[row] = s * (1.f / NN);
            dpv[row] = rp[i];
        }
    } else {
        // X column-sum partials: 64 blocks, each sums 64 rows of X[b]
        int idx = blockIdx.x - NB*CI*NN/4;   // 0..63
        int b = idx >> 4, seg = idx & 15;
        int g = threadIdx.x >> 6, x = threadIdx.x & 63;
        __shared__ float red[4][64];
        float s = 0.f;
        #pragma unroll
        for (int k = 0; k < 16; k++) {
            int i = seg*64 + g*16 + k;
            s += X[((size_t)b*NN + i)*XD + x];
        }
        red[g][x] = s;
        __syncthreads();
        if (threadIdx.x < 64)
            Xpart[idx*64 + threadIdx.x] =
                red[0][threadIdx.x]+red[1][threadIdx.x]+red[2][threadIdx.x]+red[3][threadIdx.x];
    }
}

// ---------------- K2: per-batch constants ----------------
__global__ __launch_bounds__(256) void k_batchstats(
    const float* __restrict__ Xpart,
    const float* __restrict__ moc, const float* __restrict__ dpv,
    const float* __restrict__ AW2, const float* __restrict__ AW4, const float* __restrict__ AW7,
    const float* __restrict__ Abias,
    const float* __restrict__ X1W2, const float* __restrict__ X1W5, const float* __restrict__ X1W6,
    const float* __restrict__ X1b,
    const float* __restrict__ X2W2, const float* __restrict__ X2W5, const float* __restrict__ X2W6,
    const float* __restrict__ X2b,
    float* __restrict__ constA_o, float* __restrict__ cx1_o, float* __restrict__ cx2_o)
{
    int b = blockIdx.x, tid = threadIdx.x;
    __shared__ float sdp[8][32], smoc[8][32];
    __shared__ float mdp_s[8], mall_s[8], mx_s[64];
    {
        int c = tid >> 5, rr = tid & 31;
        float pd = 0.f, pm = 0.f;
        for (int i = rr; i < NN; i += 32) {
            pd += dpv[(b*CI + c)*NN + i];
            pm += moc[(b*CI + c)*NN + i];
        }
        sdp[c][rr] = pd; smoc[c][rr] = pm;
    }
    if (tid < 64) {
        float px = 0.f;
        #pragma unroll
        for (int s = 0; s < 16; s++) px += Xpart[(b*16 + s)*64 + tid];
        mx_s[tid] = px * (1.f/NN);
    }
    __syncthreads();
    if (tid < 8) {
        float sd = 0.f, sm = 0.f;
        for (int k = 0; k < 32; k++) { sd += sdp[tid][k]; sm += smoc[tid][k]; }
        mdp_s[tid] = sd * (1.f/NN); mall_s[tid] = sm * (1.f/NN);
    }
    __syncthreads();
    if (tid < SO) {
        float v = Abias[tid];
        #pragma unroll
        for (int c = 0; c < 8; c++)
            v += mall_s[c]*AW2[c*SO+tid] + mdp_s[c]*AW4[c*SO+tid];
        for (int x = 0; x < 64; x++) v += mx_s[x]*AW7[x*SO+tid];
        constA_o[b*SO + tid] = v;
    }
    if (tid < 64) {
        float v1 = X1b[tid], v2 = X2b[tid];
        for (int x = 0; x < 64; x++) {
            float m = mx_s[x];
            v1 += m*X1W2[x*64+tid];
            v2 += m*X2W2[x*64+tid];
        }
        #pragma unroll
        for (int c = 0; c < 8; c++) {
            v1 += mall_s[c]*X1W6[c*64+tid] + mdp_s[c]*X1W5[c*64+tid];
            v2 += mall_s[c]*X2W6[c*64+tid] + mdp_s[c]*X2W5[c*64+tid];
        }
        cx1_o[b*64+tid] = v1; cx2_o[b*64+tid] = v2;
    }
}

// ---------------- K3: per-node row quantities: pairA, X1t, X2t^T ----------------
__global__ __launch_bounds__(256) void k_rows(const float* __restrict__ X,
    const float* __restrict__ moc, const float* __restrict__ dpv,
    const float* __restrict__ AW3, const float* __restrict__ AW5, const float* __restrict__ AW6,
    const float* __restrict__ X1W1, const float* __restrict__ X1W3, const float* __restrict__ X1W4,
    const float* __restrict__ X2W1, const float* __restrict__ X2W3, const float* __restrict__ X2W4,
    const float* __restrict__ cx1, const float* __restrict__ cx2,
    float* __restrict__ X1t, u16* __restrict__ X2tT,
    float* __restrict__ pairA, float* __restrict__ pairAT)
{
    int wave = threadIdx.x >> 6, u = threadIdx.x & 63;
    int r = blockIdx.x * 4 + wave;
    int b = r >> 10, i = r & (NN - 1);
    float xv = X[(size_t)r*XD + u];
    float a1 = cx1[b*XD + u], a2 = cx2[b*XD + u];
    int s = u & 15;
    float pa = 0.f;
    for (int x = 0; x < XD; x++) {
        float xx = __shfl(xv, x);
        a1 += xx * X1W1[x*XD + u];
        a2 += xx * X2W1[x*XD + u];
        pa += xx * AW6[x*SO + s];
    }
    #pragma unroll
    for (int c = 0; c < CI; c++) {
        float mv = moc[(b*CI + c)*NN + i];
        float dv = dpv[(b*CI + c)*NN + i];
        a1 += mv*X1W3[c*XD+u] + dv*X1W4[c*XD+u];
        a2 += mv*X2W3[c*XD+u] + dv*X2W4[c*XD+u];
        pa += mv*AW3[c*SO+s] + dv*AW5[c*SO+s];
    }
    X1t[(size_t)r*XD + u] = a1;
    X2tT[((size_t)b*XD + u)*NN + i] = f2bf(a2);
    if (u < SO) {
        pairA[(size_t)r*SO + u] = pa;
        pairAT[((size_t)b*SO + u)*NN + i] = pa;
    }
}

// ---------------- K4a: H[b,s,t] = sum_i pairAT[b,s,i]*X2t[b,t,i]; s2[b,t] = sum_i X2t[b,t,i] ----------------
__global__ __launch_bounds__(256) void k_H(const float* __restrict__ pairAT,
                                           const u16* __restrict__ X2tT,
                                           float* __restrict__ H, float* __restrict__ s2)
{
    __shared__ float red[4][64];
    int tid = threadIdx.x;
    int t = tid & 63, g = tid >> 6;
    if (blockIdx.x < 64) {
        int b = blockIdx.x >> 4, s = blockIdx.x & 15;
        const u16* x2 = X2tT + ((size_t)(b*XD) + t)*NN;
        const float* par = pairAT + ((size_t)(b*SO) + s)*NN;
        float h = 0.f;
        for (int i = g*256; i < (g+1)*256; i += 8) {
            bf16x8 v = __builtin_bit_cast(bf16x8, *(const uint4*)(x2 + i));
            f32x4 p0 = *(const f32x4*)(par + i);
            f32x4 p1 = *(const f32x4*)(par + i + 4);
            #pragma unroll
            for (int e = 0; e < 4; e++)
                h += p0[e]*bf2f((u16)v[e]) + p1[e]*bf2f((u16)v[e+4]);
        }
        red[g][t] = h;
        __syncthreads();
        if (tid < 64)
            H[((size_t)(b*SO) + s)*64 + tid] = red[0][tid]+red[1][tid]+red[2][tid]+red[3][tid];
    } else {
        int b = blockIdx.x - 64;
        const u16* x2 = X2tT + ((size_t)(b*XD) + t)*NN;
        float p = 0.f;
        for (int i = g*256; i < (g+1)*256; i += 8) {
            bf16x8 v = __builtin_bit_cast(bf16x8, *(const uint4*)(x2 + i));
            #pragma unroll
            for (int e = 0; e < 8; e++) p += bf2f((u16)v[e]);
        }
        red[g][t] = p;
        __syncthreads();
        if (tid < 64)
            s2[b*64 + tid] = red[0][tid]+red[1][tid]+red[2][tid]+red[3][tid];
    }
}

// ---------------- K4b: K1, C2 (blocks 0-3) + fused weights WGT (blocks 4-131) ----------------
__global__ __launch_bounds__(256) void k_small2(const float* __restrict__ Wo, const float* __restrict__ AW1,
    const float* __restrict__ constA, const float* __restrict__ H, const float* __restrict__ s2,
    float* __restrict__ K1, float* __restrict__ C2, u16* __restrict__ WGT)
{
    int tid = threadIdx.x;
    if (blockIdx.x < 4) {
        int b = blockIdx.x;
        __shared__ float ls[4][64];
        int t = tid & 63, g = tid >> 6;
        const float* s2b = s2 + b*64;
        float pc = 0.f;
        #pragma unroll
        for (int si = 0; si < 4; si++) {
            int s = g*4 + si;
            float ca = constA[b*SO + s];
            const float* Hs = H + ((size_t)(b*SO) + s)*64;
            float v = 0.f;
            for (int tt = 0; tt < 64; tt++) {
                float w = Wo[(s*64+tt)*64 + t];
                v  += s2b[tt] * w;
                pc += (Hs[tt] + ca*s2b[tt]) * w;
            }
            K1[((size_t)(b*SO) + s)*XD + t] = v;
        }
        ls[g][t] = pc;
        __syncthreads();
        if (tid < 64) C2[b*XD + tid] = (ls[0][tid]+ls[1][tid]+ls[2][tid]+ls[3][tid]) * (1.f/NN);
    } else {
        int o = (blockIdx.x - 4)*256 + tid;     // 0..32767
        int u = o >> 9;
        int k = o & 511;
        int c = k >> 6, t = k & 63;
        float v = 0.f;
        #pragma unroll
        for (int s = 0; s < SO; s++) v += AW1[c*SO+s] * Wo[(s*64+t)*64 + u];
        WGT[(size_t)u*512 + k] = f2bf(v);
    }
}

// ---------------- K5: fused At writer + G MFMA + out1 epilogue (16 waves) ----------------
// Grid: 256 blocks = (b, i-tile of 16 rows). 1024 threads = 16 waves:
//   nt = wave&3 (t/s quarter), jq = wave>>2 (j QUARTER, 256 cols, 8 steps).
// j partitions A's columns -> A still read exactly once per i-tile (no duplication).
// __launch_bounds__(1024) WITHOUT a min-waves arg: the 1024-thread block itself forces a
// 128-VGPR cap (16 waves at 4/SIMD); round-4's (1024,4) made the compiler pick 64 VGPR
// and spill the A-buffer to scratch (+440 MB memory traffic). 16 waves/CU, spill-free.
// G reduced over the 4 j-quarters via serial LDS accumulation (3 barriers), then
// bf16 Gb tile feeds the out1 MFMA epilogue on the jq==0 waves.
__global__ __launch_bounds__(1024) void k_fused(
    const float* __restrict__ A, const u16* __restrict__ X2tT,
    const float* __restrict__ AW1,
    const float* __restrict__ pairA, const float* __restrict__ pairAT,
    const float* __restrict__ constA,
    const u16* __restrict__ WGT, const float* __restrict__ K1,
    const float* __restrict__ C2, const float* __restrict__ X1t,
    const float* __restrict__ outb,
    float* __restrict__ out0, float* __restrict__ out1)
{
    __shared__ float W1s[CI][SO];
    __shared__ __align__(16) float Gsh[4][CI][64][4];   // 32 KB: [nt][c][lane][reg]
    __shared__ __align__(16) u16 Gb[16][520];           // 16.6 KB, +8 col pad

    int tid = threadIdx.x;
    int wave = tid >> 6, lane = tid & 63;
    int lr = lane & 15, lq = lane >> 4;
    int nt = wave & 3, jq = wave >> 2;                  // jq in [0,4)
    int b = blockIdx.x >> 6;
    int i0 = (blockIdx.x & 63) * 16;
    int s4 = nt * 4;

    if (tid < CI*SO) W1s[tid >> 4][tid & 15] = AW1[tid];

    float rc[4];
    {
        f32x4 t = *(const f32x4*)(pairA + ((size_t)(b*NN) + i0 + lr)*SO + s4);
        const float* ca = constA + b*SO + s4;
        #pragma unroll
        for (int s = 0; s < 4; s++) rc[s] = t[s] + ca[s];
    }
    __syncthreads();   // W1s ready

    const float* Ab = A + ((size_t)b*CI)*NN*NN + (size_t)(i0 + lr)*NN;
    const u16*  Xb = X2tT + ((size_t)(b*XD) + nt*16 + lr)*NN;

    f32x4 acc[CI];
    #pragma unroll
    for (int c = 0; c < CI; c++) acc[c] = (f32x4){0.f,0.f,0.f,0.f};

    for (int st = 0; st < 8; st++) {
        int j0 = jq*256 + st*32 + lq*8;
        f32x4 a0[CI], a1[CI];
        #pragma unroll
        for (int c = 0; c < CI; c++) {
            const float* ar = Ab + (size_t)c*NN*NN + j0;
            a0[c] = *(const f32x4*)ar;
            a1[c] = *(const f32x4*)(ar + 4);
        }
        bf16x8 bfr = __builtin_bit_cast(bf16x8, *(const uint4*)(Xb + j0));
        // At: this wave owns s in [s4, s4+4), rows i0+lr, cols j0..j0+7
        #pragma unroll
        for (int s = 0; s < 4; s++) {
            const float* pt = pairAT + ((size_t)(b*SO) + s4 + s)*NN + j0;
            f32x4 p0 = *(const f32x4*)pt;
            f32x4 p1 = *(const f32x4*)(pt + 4);
            f32x4 o0, o1;
            #pragma unroll
            for (int e = 0; e < 4; e++) { o0[e] = rc[s] + p0[e]; o1[e] = rc[s] + p1[e]; }
            #pragma unroll
            for (int c = 0; c < CI; c++) {
                float wv = W1s[c][s4 + s];
                #pragma unroll
                for (int e = 0; e < 4; e++) { o0[e] += a0[c][e]*wv; o1[e] += a1[c][e]*wv; }
            }
            float* op = out0 + (((size_t)(b*SO + s4 + s))*NN + i0 + lr)*NN + j0;
            *(f32x4*)op = o0;
            *(f32x4*)(op + 4) = o1;
        }
        // G MFMA: bf16 fragments from the same registers
        #pragma unroll
        for (int c = 0; c < CI; c++) {
            bf16x8 af;
            #pragma unroll
            for (int e = 0; e < 4; e++) { af[e] = (short)f2bf(a0[c][e]); af[e+4] = (short)f2bf(a1[c][e]); }
            acc[c] = __builtin_amdgcn_mfma_f32_16x16x32_bf16(af, bfr, acc[c], 0, 0, 0);
        }
    }

    // ---- reduce the 4 j-quarters serially in LDS ----
    if (jq == 3) {
        #pragma unroll
        for (int c = 0; c < CI; c++)
            *(f32x4*)&Gsh[nt][c][lane][0] = acc[c];
    }
    __syncthreads();
    if (jq == 2) {
        #pragma unroll
        for (int c = 0; c < CI; c++) {
            f32x4 g = *(const f32x4*)&Gsh[nt][c][lane][0];
            #pragma unroll
            for (int e = 0; e < 4; e++) g[e] += acc[c][e];
            *(f32x4*)&Gsh[nt][c][lane][0] = g;
        }
    }
    __syncthreads();
    if (jq == 1) {
        #pragma unroll
        for (int c = 0; c < CI; c++) {
            f32x4 g = *(const f32x4*)&Gsh[nt][c][lane][0];
            #pragma unroll
            for (int e = 0; e < 4; e++) g[e] += acc[c][e];
            *(f32x4*)&Gsh[nt][c][lane][0] = g;
        }
    }
    __syncthreads();
    if (jq == 0) {
        #pragma unroll
        for (int c = 0; c < CI; c++) {
            f32x4 g = *(const f32x4*)&Gsh[nt][c][lane][0];
            #pragma unroll
            for (int reg = 0; reg < 4; reg++)
                Gb[lq*4 + reg][c*64 + nt*16 + lr] = f2bf(acc[c][reg] + g[reg]);
        }
    }
    __syncthreads();

    // ---- out1 epilogue (jq==0 waves; 16 rows x 64 u, K=512) ----
    if (jq == 0) {
        f32x4 acc1 = (f32x4){0.f,0.f,0.f,0.f};
        #pragma unroll
        for (int k0 = 0; k0 < 512; k0 += 32) {
            bf16x8 ga = __builtin_bit_cast(bf16x8, *(const uint4*)&Gb[lr][k0 + lq*8]);
            bf16x8 wb = __builtin_bit_cast(bf16x8,
                *(const uint4*)(WGT + (size_t)(nt*16 + lr)*512 + k0 + lq*8));
            acc1 = __builtin_amdgcn_mfma_f32_16x16x32_bf16(ga, wb, acc1, 0, 0, 0);
        }
        int u = nt*16 + lr;
        float k1c[SO];
        #pragma unroll
        for (int s = 0; s < SO; s++) k1c[s] = K1[((size_t)(b*SO) + s)*XD + u];
        float cb = C2[b*XD + u] + outb[u];
        #pragma unroll
        for (int reg = 0; reg < 4; reg++) {
            int ii = i0 + lq*4 + reg;
            const float* pa = pairA + ((size_t)(b*NN) + ii)*SO;
            float s16 = 0.f;
            #pragma unroll
            for (int s = 0; s < SO; s++) s16 += pa[s] * k1c[s];
            out1[((size_t)(b*NN) + ii)*XD + u] =
                (acc1[reg] + s16) * (1.f/NN) + cb
                + X1t[((size_t)(b*NN) + ii)*XD + u];
        }
    }
}

extern "C" void kernel_launch(void* const* d_in, const int* in_sizes, int n_in,
                              void* d_out, int out_size, void* d_ws, size_t ws_size,
                              hipStream_t stream)
{
    const float* A     = (const float*)d_in[0];
    const float* X     = (const float*)d_in[1];
    const float* AW1   = (const float*)d_in[2];
    const float* AW2   = (const float*)d_in[3];
    const float* AW3   = (const float*)d_in[4];
    const float* AW4   = (const float*)d_in[5];
    const float* AW5   = (const float*)d_in[6];
    const float* AW6   = (const float*)d_in[7];
    const float* AW7   = (const float*)d_in[8];
    const float* Abias = (const float*)d_in[9];
    const float* X1W1  = (const float*)d_in[10];
    const float* X1W2  = (const float*)d_in[11];
    const float* X1W3  = (const float*)d_in[12];
    const float* X1W4  = (const float*)d_in[13];
    const float* X1W5  = (const float*)d_in[14];
    const float* X1W6  = (const float*)d_in[15];
    const float* X1b   = (const float*)d_in[16];
    const float* X2W1  = (const float*)d_in[17];
    const float* X2W2  = (const float*)d_in[18];
    const float* X2W3  = (const float*)d_in[19];
    const float* X2W4  = (const float*)d_in[20];
    const float* X2W5  = (const float*)d_in[21];
    const float* X2W6  = (const float*)d_in[22];
    const float* X2b   = (const float*)d_in[23];
    const float* Wo    = (const float*)d_in[24];
    const float* outb  = (const float*)d_in[25];

    char* ws = (char*)d_ws;
    float* moc    = (float*)(ws + WS_MOC);
    float* dpv    = (float*)(ws + WS_DP);
    float* constA = (float*)(ws + WS_CONSTA);
    float* cx1    = (float*)(ws + WS_CX1);
    float* cx2    = (float*)(ws + WS_CX2);
    float* K1     = (float*)(ws + WS_K1);
    float* C2     = (float*)(ws + WS_C2);
    float* pairA  = (float*)(ws + WS_PAIRA);
    float* pairAT = (float*)(ws + WS_PAIRAT);
    float* X1t    = (float*)(ws + WS_X1T);
    u16*   X2tT   = (u16*)(ws + WS_X2TT);
    u16*   WGT    = (u16*)(ws + WS_WGT);
    float* H      = (float*)(ws + WS_H);
    float* Xpart  = (float*)(ws + WS_XPART);
    float* s2     = (float*)(ws + WS_S2);

    float* out0 = (float*)d_out;
    float* out1 = out0 + (size_t)NB*SO*NN*NN;

    k_rowstats<<<dim3(NB*CI*NN/4 + 64), dim3(256), 0, stream>>>(A, X, moc, dpv, Xpart);
    k_batchstats<<<dim3(NB), dim3(256), 0, stream>>>(Xpart, moc, dpv,
        AW2, AW4, AW7, Abias, X1W2, X1W5, X1W6, X1b, X2W2, X2W5, X2W6, X2b,
        constA, cx1, cx2);
    k_rows<<<dim3(NB*NN/4), dim3(256), 0, stream>>>(X, moc, dpv,
        AW3, AW5, AW6, X1W1, X1W3, X1W4, X2W1, X2W3, X2W4, cx1, cx2,
        X1t, X2tT, pairA, pairAT);
    k_H<<<dim3(68), dim3(256), 0, stream>>>(pairAT, X2tT, H, s2);
    k_small2<<<dim3(132), dim3(256), 0, stream>>>(Wo, AW1, constA, H, s2, K1, C2, WGT);
    k_fused<<<dim3(NB*NN/16), dim3(1024), 0, stream>>>(A, X2tT, AW1,
        pairA, pairAT, constA, WGT, K1, C2, X1t, outb, out0, out1);
}

// Round 6
// 790.108 us; speedup vs baseline: 1.0232x; 1.0232x over previous
//
#include <hip/hip_runtime.h>

// GNN_layer: N=4, A_IN=8, A_OUT=16, X=64, n=1024.
// Inputs: float32. Outputs: float32 (reference output dtype).
// Decomposition:
//   At[b,i,j,s] = Base + pairA[i,s] + pairA[j,s] + constA[s],  Base = sum_c A[b,c,i,j] W1[c,s]
//   einsum factors through G[b,c,i,t] = A[b,c] @ X2t (MFMA, A cast to bf16 in-reg).
// ROUND 6: round 4/5 proved the compiler's default for 1024-thread blocks is 64 VGPR
// (targets 2 blocks/CU) and it spills the 64-reg A-buffer to scratch (+880 MB traffic,
// 413 us). Neither __launch_bounds__(1024) nor (1024,4) overrides that. This round pins
// the allocator with __attribute__((amdgpu_waves_per_eu(4,4))): exactly 4 waves/EU ->
// VGPR cap 512/4 = 128, the budget where round-3's identical loop body was spill-free.
// 16 waves/CU at 128 VGPR = full register file, 1 block/CU. Everything else unchanged.

#define NB 4
#define CI 8
#define SO 16
#define XD 64
#define NN 1024

typedef unsigned short u16;
typedef unsigned int u32;
typedef float f32x4 __attribute__((ext_vector_type(4)));
typedef short bf16x8 __attribute__((ext_vector_type(8)));

// ---- workspace layout (bytes), total <= 0x660000 = 6.7 MB ----
#define WS_MOC    0x000000u  // f32[4*8*1024]
#define WS_DP     0x020000u  // f32[4*8*1024]
#define WS_CONSTA 0x043000u  // f32[4*16]
#define WS_CX1    0x044000u  // f32[4*64]
#define WS_CX2    0x045000u  // f32[4*64]
#define WS_K1     0x048000u  // f32[4*16*64]
#define WS_C2     0x04C000u  // f32[4*64]
#define WS_PAIRA  0x050000u  // f32[4*1024*16]
#define WS_PAIRAT 0x090000u  // f32[4*16*1024]
#define WS_X1T    0x0D0000u  // f32[4*1024*64]
#define WS_X2TT   0x1D0000u  // bf16[4*64*1024]
#define WS_WGT    0x250000u  // bf16[64*512]
#define WS_H      0x260000u  // f32[4*16*64]   (16 KB)
#define WS_XPART  0x264000u  // f32[64*64]     (16 KB)
#define WS_S2     0x268000u  // f32[4*64]      (1 KB)

__device__ __forceinline__ float bf2f(u16 u){ return __uint_as_float(((u32)u) << 16); }
__device__ __forceinline__ u16 f2bf(float f){
    u32 x = __float_as_uint(f);
    x += 0x7fffu + ((x >> 16) & 1u);
    return (u16)(x >> 16);
}

// ---------------- K1: per-row stats of A (moc, dp) + X column-sum partials ----------------
__global__ __launch_bounds__(256) void k_rowstats(const float* __restrict__ A,
                                                  const float* __restrict__ X,
                                                  float* __restrict__ moc,
                                                  float* __restrict__ dpv,
                                                  float* __restrict__ Xpart)
{
    if (blockIdx.x < NB*CI*NN/4) {
        int wave = threadIdx.x >> 6, lane = threadIdx.x & 63;
        int row = blockIdx.x * 4 + wave;           // (b*8+c)*1024 + i
        int i = row & (NN - 1);
        const float* rp = A + (size_t)row * NN;
        f32x4 v0 = *(const f32x4*)(rp + lane * 16);
        f32x4 v1 = *(const f32x4*)(rp + lane * 16 + 4);
        f32x4 v2 = *(const f32x4*)(rp + lane * 16 + 8);
        f32x4 v3 = *(const f32x4*)(rp + lane * 16 + 12);
        float s = 0.f;
        #pragma unroll
        for (int e = 0; e < 4; e++) s += v0[e] + v1[e] + v2[e] + v3[e];
        #pragma unroll
        for (int off = 32; off; off >>= 1) s += __shfl_down(s, off);
        if (lane == 0) {
            moc[row] = s * (1.f / NN);
            dpv[row] = rp[i];
        }
    } else {
        // X column-sum partials: 64 blocks, each sums 64 rows of X[b]
        int idx = blockIdx.x - NB*CI*NN/4;   // 0..63
        int b = idx >> 4, seg = idx & 15;
        int g = threadIdx.x >> 6, x = threadIdx.x & 63;
        __shared__ float red[4][64];
        float s = 0.f;
        #pragma unroll
        for (int k = 0; k < 16; k++) {
            int i = seg*64 + g*16 + k;
            s += X[((size_t)b*NN + i)*XD + x];
        }
        red[g][x] = s;
        __syncthreads();
        if (threadIdx.x < 64)
            Xpart[idx*64 + threadIdx.x] =
                red[0][threadIdx.x]+red[1][threadIdx.x]+red[2][threadIdx.x]+red[3][threadIdx.x];
    }
}

// ---------------- K2: per-batch constants ----------------
__global__ __launch_bounds__(256) void k_batchstats(
    const float* __restrict__ Xpart,
    const float* __restrict__ moc, const float* __restrict__ dpv,
    const float* __restrict__ AW2, const float* __restrict__ AW4, const float* __restrict__ AW7,
    const float* __restrict__ Abias,
    const float* __restrict__ X1W2, const float* __restrict__ X1W5, const float* __restrict__ X1W6,
    const float* __restrict__ X1b,
    const float* __restrict__ X2W2, const float* __restrict__ X2W5, const float* __restrict__ X2W6,
    const float* __restrict__ X2b,
    float* __restrict__ constA_o, float* __restrict__ cx1_o, float* __restrict__ cx2_o)
{
    int b = blockIdx.x, tid = threadIdx.x;
    __shared__ float sdp[8][32], smoc[8][32];
    __shared__ float mdp_s[8], mall_s[8], mx_s[64];
    {
        int c = tid >> 5, rr = tid & 31;
        float pd = 0.f, pm = 0.f;
        for (int i = rr; i < NN; i += 32) {
            pd += dpv[(b*CI + c)*NN + i];
            pm += moc[(b*CI + c)*NN + i];
        }
        sdp[c][rr] = pd; smoc[c][rr] = pm;
    }
    if (tid < 64) {
        float px = 0.f;
        #pragma unroll
        for (int s = 0; s < 16; s++) px += Xpart[(b*16 + s)*64 + tid];
        mx_s[tid] = px * (1.f/NN);
    }
    __syncthreads();
    if (tid < 8) {
        float sd = 0.f, sm = 0.f;
        for (int k = 0; k < 32; k++) { sd += sdp[tid][k]; sm += smoc[tid][k]; }
        mdp_s[tid] = sd * (1.f/NN); mall_s[tid] = sm * (1.f/NN);
    }
    __syncthreads();
    if (tid < SO) {
        float v = Abias[tid];
        #pragma unroll
        for (int c = 0; c < 8; c++)
            v += mall_s[c]*AW2[c*SO+tid] + mdp_s[c]*AW4[c*SO+tid];
        for (int x = 0; x < 64; x++) v += mx_s[x]*AW7[x*SO+tid];
        constA_o[b*SO + tid] = v;
    }
    if (tid < 64) {
        float v1 = X1b[tid], v2 = X2b[tid];
        for (int x = 0; x < 64; x++) {
            float m = mx_s[x];
            v1 += m*X1W2[x*64+tid];
            v2 += m*X2W2[x*64+tid];
        }
        #pragma unroll
        for (int c = 0; c < 8; c++) {
            v1 += mall_s[c]*X1W6[c*64+tid] + mdp_s[c]*X1W5[c*64+tid];
            v2 += mall_s[c]*X2W6[c*64+tid] + mdp_s[c]*X2W5[c*64+tid];
        }
        cx1_o[b*64+tid] = v1; cx2_o[b*64+tid] = v2;
    }
}

// ---------------- K3: per-node row quantities: pairA, X1t, X2t^T ----------------
__global__ __launch_bounds__(256) void k_rows(const float* __restrict__ X,
    const float* __restrict__ moc, const float* __restrict__ dpv,
    const float* __restrict__ AW3, const float* __restrict__ AW5, const float* __restrict__ AW6,
    const float* __restrict__ X1W1, const float* __restrict__ X1W3, const float* __restrict__ X1W4,
    const float* __restrict__ X2W1, const float* __restrict__ X2W3, const float* __restrict__ X2W4,
    const float* __restrict__ cx1, const float* __restrict__ cx2,
    float* __restrict__ X1t, u16* __restrict__ X2tT,
    float* __restrict__ pairA, float* __restrict__ pairAT)
{
    int wave = threadIdx.x >> 6, u = threadIdx.x & 63;
    int r = blockIdx.x * 4 + wave;
    int b = r >> 10, i = r & (NN - 1);
    float xv = X[(size_t)r*XD + u];
    float a1 = cx1[b*XD + u], a2 = cx2[b*XD + u];
    int s = u & 15;
    float pa = 0.f;
    for (int x = 0; x < XD; x++) {
        float xx = __shfl(xv, x);
        a1 += xx * X1W1[x*XD + u];
        a2 += xx * X2W1[x*XD + u];
        pa += xx * AW6[x*SO + s];
    }
    #pragma unroll
    for (int c = 0; c < CI; c++) {
        float mv = moc[(b*CI + c)*NN + i];
        float dv = dpv[(b*CI + c)*NN + i];
        a1 += mv*X1W3[c*XD+u] + dv*X1W4[c*XD+u];
        a2 += mv*X2W3[c*XD+u] + dv*X2W4[c*XD+u];
        pa += mv*AW3[c*SO+s] + dv*AW5[c*SO+s];
    }
    X1t[(size_t)r*XD + u] = a1;
    X2tT[((size_t)b*XD + u)*NN + i] = f2bf(a2);
    if (u < SO) {
        pairA[(size_t)r*SO + u] = pa;
        pairAT[((size_t)b*SO + u)*NN + i] = pa;
    }
}

// ---------------- K4a: H[b,s,t] = sum_i pairAT[b,s,i]*X2t[b,t,i]; s2[b,t] = sum_i X2t[b,t,i] ----------------
__global__ __launch_bounds__(256) void k_H(const float* __restrict__ pairAT,
                                           const u16* __restrict__ X2tT,
                                           float* __restrict__ H, float* __restrict__ s2)
{
    __shared__ float red[4][64];
    int tid = threadIdx.x;
    int t = tid & 63, g = tid >> 6;
    if (blockIdx.x < 64) {
        int b = blockIdx.x >> 4, s = blockIdx.x & 15;
        const u16* x2 = X2tT + ((size_t)(b*XD) + t)*NN;
        const float* par = pairAT + ((size_t)(b*SO) + s)*NN;
        float h = 0.f;
        for (int i = g*256; i < (g+1)*256; i += 8) {
            bf16x8 v = __builtin_bit_cast(bf16x8, *(const uint4*)(x2 + i));
            f32x4 p0 = *(const f32x4*)(par + i);
            f32x4 p1 = *(const f32x4*)(par + i + 4);
            #pragma unroll
            for (int e = 0; e < 4; e++)
                h += p0[e]*bf2f((u16)v[e]) + p1[e]*bf2f((u16)v[e+4]);
        }
        red[g][t] = h;
        __syncthreads();
        if (tid < 64)
            H[((size_t)(b*SO) + s)*64 + tid] = red[0][tid]+red[1][tid]+red[2][tid]+red[3][tid];
    } else {
        int b = blockIdx.x - 64;
        const u16* x2 = X2tT + ((size_t)(b*XD) + t)*NN;
        float p = 0.f;
        for (int i = g*256; i < (g+1)*256; i += 8) {
            bf16x8 v = __builtin_bit_cast(bf16x8, *(const uint4*)(x2 + i));
            #pragma unroll
            for (int e = 0; e < 8; e++) p += bf2f((u16)v[e]);
        }
        red[g][t] = p;
        __syncthreads();
        if (tid < 64)
            s2[b*64 + tid] = red[0][tid]+red[1][tid]+red[2][tid]+red[3][tid];
    }
}

// ---------------- K4b: K1, C2 (blocks 0-3) + fused weights WGT (blocks 4-131) ----------------
__global__ __launch_bounds__(256) void k_small2(const float* __restrict__ Wo, const float* __restrict__ AW1,
    const float* __restrict__ constA, const float* __restrict__ H, const float* __restrict__ s2,
    float* __restrict__ K1, float* __restrict__ C2, u16* __restrict__ WGT)
{
    int tid = threadIdx.x;
    if (blockIdx.x < 4) {
        int b = blockIdx.x;
        __shared__ float ls[4][64];
        int t = tid & 63, g = tid >> 6;
        const float* s2b = s2 + b*64;
        float pc = 0.f;
        #pragma unroll
        for (int si = 0; si < 4; si++) {
            int s = g*4 + si;
            float ca = constA[b*SO + s];
            const float* Hs = H + ((size_t)(b*SO) + s)*64;
            float v = 0.f;
            for (int tt = 0; tt < 64; tt++) {
                float w = Wo[(s*64+tt)*64 + t];
                v  += s2b[tt] * w;
                pc += (Hs[tt] + ca*s2b[tt]) * w;
            }
            K1[((size_t)(b*SO) + s)*XD + t] = v;
        }
        ls[g][t] = pc;
        __syncthreads();
        if (tid < 64) C2[b*XD + tid] = (ls[0][tid]+ls[1][tid]+ls[2][tid]+ls[3][tid]) * (1.f/NN);
    } else {
        int o = (blockIdx.x - 4)*256 + tid;     // 0..32767
        int u = o >> 9;
        int k = o & 511;
        int c = k >> 6, t = k & 63;
        float v = 0.f;
        #pragma unroll
        for (int s = 0; s < SO; s++) v += AW1[c*SO+s] * Wo[(s*64+t)*64 + u];
        WGT[(size_t)u*512 + k] = f2bf(v);
    }
}

// ---------------- K5: fused At writer + G MFMA + out1 epilogue (16 waves) ----------------
// Grid: 256 blocks = (b, i-tile of 16 rows). 1024 threads = 16 waves:
//   nt = wave&3 (t/s quarter), jq = wave>>2 (j QUARTER, 256 cols, 8 steps).
// j partitions A's columns -> A still read exactly once per i-tile (no duplication).
// amdgpu_waves_per_eu(4,4): pin exactly 4 waves/EU -> VGPR cap 512/4 = 128. The default
// heuristic picks 64 VGPR (targets 2 blocks/CU) and spills the 64-reg A-buffer to scratch
// (rounds 4/5: +880 MB traffic, 413 us). Round 3's identical loop body was spill-free at 128.
// G reduced over the 4 j-quarters via serial LDS accumulation (3 barriers), then
// bf16 Gb tile feeds the out1 MFMA epilogue on the jq==0 waves.
__global__ __launch_bounds__(1024)
__attribute__((amdgpu_waves_per_eu(4, 4)))
void k_fused(
    const float* __restrict__ A, const u16* __restrict__ X2tT,
    const float* __restrict__ AW1,
    const float* __restrict__ pairA, const float* __restrict__ pairAT,
    const float* __restrict__ constA,
    const u16* __restrict__ WGT, const float* __restrict__ K1,
    const float* __restrict__ C2, const float* __restrict__ X1t,
    const float* __restrict__ outb,
    float* __restrict__ out0, float* __restrict__ out1)
{
    __shared__ float W1s[CI][SO];
    __shared__ __align__(16) float Gsh[4][CI][64][4];   // 32 KB: [nt][c][lane][reg]
    __shared__ __align__(16) u16 Gb[16][520];           // 16.6 KB, +8 col pad

    int tid = threadIdx.x;
    int wave = tid >> 6, lane = tid & 63;
    int lr = lane & 15, lq = lane >> 4;
    int nt = wave & 3, jq = wave >> 2;                  // jq in [0,4)
    int b = blockIdx.x >> 6;
    int i0 = (blockIdx.x & 63) * 16;
    int s4 = nt * 4;

    if (tid < CI*SO) W1s[tid >> 4][tid & 15] = AW1[tid];

    float rc[4];
    {
        f32x4 t = *(const f32x4*)(pairA + ((size_t)(b*NN) + i0 + lr)*SO + s4);
        const float* ca = constA + b*SO + s4;
        #pragma unroll
        for (int s = 0; s < 4; s++) rc[s] = t[s] + ca[s];
    }
    __syncthreads();   // W1s ready

    const float* Ab = A + ((size_t)b*CI)*NN*NN + (size_t)(i0 + lr)*NN;
    const u16*  Xb = X2tT + ((size_t)(b*XD) + nt*16 + lr)*NN;

    f32x4 acc[CI];
    #pragma unroll
    for (int c = 0; c < CI; c++) acc[c] = (f32x4){0.f,0.f,0.f,0.f};

    for (int st = 0; st < 8; st++) {
        int j0 = jq*256 + st*32 + lq*8;
        f32x4 a0[CI], a1[CI];
        #pragma unroll
        for (int c = 0; c < CI; c++) {
            const float* ar = Ab + (size_t)c*NN*NN + j0;
            a0[c] = *(const f32x4*)ar;
            a1[c] = *(const f32x4*)(ar + 4);
        }
        bf16x8 bfr = __builtin_bit_cast(bf16x8, *(const uint4*)(Xb + j0));
        // At: this wave owns s in [s4, s4+4), rows i0+lr, cols j0..j0+7
        #pragma unroll
        for (int s = 0; s < 4; s++) {
            const float* pt = pairAT + ((size_t)(b*SO) + s4 + s)*NN + j0;
            f32x4 p0 = *(const f32x4*)pt;
            f32x4 p1 = *(const f32x4*)(pt + 4);
            f32x4 o0, o1;
            #pragma unroll
            for (int e = 0; e < 4; e++) { o0[e] = rc[s] + p0[e]; o1[e] = rc[s] + p1[e]; }
            #pragma unroll
            for (int c = 0; c < CI; c++) {
                float wv = W1s[c][s4 + s];
                #pragma unroll
                for (int e = 0; e < 4; e++) { o0[e] += a0[c][e]*wv; o1[e] += a1[c][e]*wv; }
            }
            float* op = out0 + (((size_t)(b*SO + s4 + s))*NN + i0 + lr)*NN + j0;
            *(f32x4*)op = o0;
            *(f32x4*)(op + 4) = o1;
        }
        // G MFMA: bf16 fragments from the same registers
        #pragma unroll
        for (int c = 0; c < CI; c++) {
            bf16x8 af;
            #pragma unroll
            for (int e = 0; e < 4; e++) { af[e] = (short)f2bf(a0[c][e]); af[e+4] = (short)f2bf(a1[c][e]); }
            acc[c] = __builtin_amdgcn_mfma_f32_16x16x32_bf16(af, bfr, acc[c], 0, 0, 0);
        }
    }

    // ---- reduce the 4 j-quarters serially in LDS ----
    if (jq == 3) {
        #pragma unroll
        for (int c = 0; c < CI; c++)
            *(f32x4*)&Gsh[nt][c][lane][0] = acc[c];
    }
    __syncthreads();
    if (jq == 2) {
        #pragma unroll
        for (int c = 0; c < CI; c++) {
            f32x4 g = *(const f32x4*)&Gsh[nt][c][lane][0];
            #pragma unroll
            for (int e = 0; e < 4; e++) g[e] += acc[c][e];
            *(f32x4*)&Gsh[nt][c][lane][0] = g;
        }
    }
    __syncthreads();
    if (jq == 1) {
        #pragma unroll
        for (int c = 0; c < CI; c++) {
            f32x4 g = *(const f32x4*)&Gsh[nt][c][lane][0];
            #pragma unroll
            for (int e = 0; e < 4; e++) g[e] += acc[c][e];
            *(f32x4*)&Gsh[nt][c][lane][0] = g;
        }
    }
    __syncthreads();
    if (jq == 0) {
        #pragma unroll
        for (int c = 0; c < CI; c++) {
            f32x4 g = *(const f32x4*)&Gsh[nt][c][lane][0];
            #pragma unroll
            for (int reg = 0; reg < 4; reg++)
                Gb[lq*4 + reg][c*64 + nt*16 + lr] = f2bf(acc[c][reg] + g[reg]);
        }
    }
    __syncthreads();

    // ---- out1 epilogue (jq==0 waves; 16 rows x 64 u, K=512) ----
    if (jq == 0) {
        f32x4 acc1 = (f32x4){0.f,0.f,0.f,0.f};
        #pragma unroll
        for (int k0 = 0; k0 < 512; k0 += 32) {
            bf16x8 ga = __builtin_bit_cast(bf16x8, *(const uint4*)&Gb[lr][k0 + lq*8]);
            bf16x8 wb = __builtin_bit_cast(bf16x8,
                *(const uint4*)(WGT + (size_t)(nt*16 + lr)*512 + k0 + lq*8));
            acc1 = __builtin_amdgcn_mfma_f32_16x16x32_bf16(ga, wb, acc1, 0, 0, 0);
        }
        int u = nt*16 + lr;
        float k1c[SO];
        #pragma unroll
        for (int s = 0; s < SO; s++) k1c[s] = K1[((size_t)(b*SO) + s)*XD + u];
        float cb = C2[b*XD + u] + outb[u];
        #pragma unroll
        for (int reg = 0; reg < 4; reg++) {
            int ii = i0 + lq*4 + reg;
            const float* pa = pairA + ((size_t)(b*NN) + ii)*SO;
            float s16 = 0.f;
            #pragma unroll
            for (int s = 0; s < SO; s++) s16 += pa[s] * k1c[s];
            out1[((size_t)(b*NN) + ii)*XD + u] =
                (acc1[reg] + s16) * (1.f/NN) + cb
                + X1t[((size_t)(b*NN) + ii)*XD + u];
        }
    }
}

extern "C" void kernel_launch(void* const* d_in, const int* in_sizes, int n_in,
                              void* d_out, int out_size, void* d_ws, size_t ws_size,
                              hipStream_t stream)
{
    const float* A     = (const float*)d_in[0];
    const float* X     = (const float*)d_in[1];
    const float* AW1   = (const float*)d_in[2];
    const float* AW2   = (const float*)d_in[3];
    const float* AW3   = (const float*)d_in[4];
    const float* AW4   = (const float*)d_in[5];
    const float* AW5   = (const float*)d_in[6];
    const float* AW6   = (const float*)d_in[7];
    const float* AW7   = (const float*)d_in[8];
    const float* Abias = (const float*)d_in[9];
    const float* X1W1  = (const float*)d_in[10];
    const float* X1W2  = (const float*)d_in[11];
    const float* X1W3  = (const float*)d_in[12];
    const float* X1W4  = (const float*)d_in[13];
    const float* X1W5  = (const float*)d_in[14];
    const float* X1W6  = (const float*)d_in[15];
    const float* X1b   = (const float*)d_in[16];
    const float* X2W1  = (const float*)d_in[17];
    const float* X2W2  = (const float*)d_in[18];
    const float* X2W3  = (const float*)d_in[19];
    const float* X2W4  = (const float*)d_in[20];
    const float* X2W5  = (const float*)d_in[21];
    const float* X2W6  = (const float*)d_in[22];
    const float* X2b   = (const float*)d_in[23];
    const float* Wo    = (const float*)d_in[24];
    const float* outb  = (const float*)d_in[25];

    char* ws = (char*)d_ws;
    float* moc    = (float*)(ws + WS_MOC);
    float* dpv    = (float*)(ws + WS_DP);
    float* constA = (float*)(ws + WS_CONSTA);
    float* cx1    = (float*)(ws + WS_CX1);
    float* cx2    = (float*)(ws + WS_CX2);
    float* K1     = (float*)(ws + WS_K1);
    float* C2     = (float*)(ws + WS_C2);
    float* pairA  = (float*)(ws + WS_PAIRA);
    float* pairAT = (float*)(ws + WS_PAIRAT);
    float* X1t    = (float*)(ws + WS_X1T);
    u16*   X2tT   = (u16*)(ws + WS_X2TT);
    u16*   WGT    = (u16*)(ws + WS_WGT);
    float* H      = (float*)(ws + WS_H);
    float* Xpart  = (float*)(ws + WS_XPART);
    float* s2     = (float*)(ws + WS_S2);

    float* out0 = (float*)d_out;
    float* out1 = out0 + (size_t)NB*SO*NN*NN;

    k_rowstats<<<dim3(NB*CI*NN/4 + 64), dim3(256), 0, stream>>>(A, X, moc, dpv, Xpart);
    k_batchstats<<<dim3(NB), dim3(256), 0, stream>>>(Xpart, moc, dpv,
        AW2, AW4, AW7, Abias, X1W2, X1W5, X1W6, X1b, X2W2, X2W5, X2W6, X2b,
        constA, cx1, cx2);
    k_rows<<<dim3(NB*NN/4), dim3(256), 0, stream>>>(X, moc, dpv,
        AW3, AW5, AW6, X1W1, X1W3, X1W4, X2W1, X2W3, X2W4, cx1, cx2,
        X1t, X2tT, pairA, pairAT);
    k_H<<<dim3(68), dim3(256), 0, stream>>>(pairAT, X2tT, H, s2);
    k_small2<<<dim3(132), dim3(256), 0, stream>>>(Wo, AW1, constA, H, s2, K1, C2, WGT);
    k_fused<<<dim3(NB*NN/16), dim3(1024), 0, stream>>>(A, X2tT, AW1,
        pairA, pairAT, constA, WGT, K1, C2, X1t, outb, out0, out1);
}

// Round 7
// 506.031 us; speedup vs baseline: 1.5976x; 1.5614x over previous
//
#include <hip/hip_runtime.h>

// GNN_layer: N=4, A_IN=8, A_OUT=16, X=64, n=1024.
// Inputs: float32. Outputs: float32 (reference output dtype).
// Decomposition:
//   At[b,i,j,s] = Base + pairA[i,s] + pairA[j,s] + constA[s],  Base = sum_c A[b,c,i,j] W1[c,s]
//   einsum factors through G[b,c,i,t] = A[b,c] @ X2t (MFMA, A cast to bf16 in-reg).
// ROUND 7: k_fused rewritten around the real limiter: address-divergent vmem.
// Evidence: 163us plateau insensitive to +-200MB of write traffic and to wave count;
// VALU-issue only ~12% of cycles; every A-load touched 16 rows 4KB apart (16 addr
// groups/instr) and was issued 4x redundantly (one copy per nt-wave). New k_fused:
//  - A staged through LDS in 64-column chunks: coalesced uint4 global loads (reg-staged,
//    issue-early/write-late) + XOR-swizzled ds_write; A read exactly once, no scatter.
//  - out0 stores coalesced: waves own i-rows, lanes span 64 contiguous j.
//  - MFMA split by channel (wave = c, acc[nt] over all j): no Gsh reduction; Gb tile
//    unions with the A-stage buffer (32KB + 8KB X2 LDS).
// 8 waves / 512 threads / 1 block/CU (the shape that compiles spill-free).

#define NB 4
#define CI 8
#define SO 16
#define XD 64
#define NN 1024

typedef unsigned short u16;
typedef unsigned int u32;
typedef float f32x4 __attribute__((ext_vector_type(4)));
typedef short bf16x8 __attribute__((ext_vector_type(8)));

// ---- workspace layout (bytes) ----
#define WS_MOC    0x000000u
#define WS_DP     0x020000u
#define WS_CONSTA 0x043000u
#define WS_CX1    0x044000u
#define WS_CX2    0x045000u
#define WS_K1     0x048000u
#define WS_C2     0x04C000u
#define WS_PAIRA  0x050000u
#define WS_PAIRAT 0x090000u
#define WS_X1T    0x0D0000u
#define WS_X2TT   0x1D0000u
#define WS_WGT    0x250000u
#define WS_H      0x260000u
#define WS_XPART  0x264000u
#define WS_S2     0x268000u

__device__ __forceinline__ float bf2f(u16 u){ return __uint_as_float(((u32)u) << 16); }
__device__ __forceinline__ u16 f2bf(float f){
    u32 x = __float_as_uint(f);
    x += 0x7fffu + ((x >> 16) & 1u);
    return (u16)(x >> 16);
}

// ---------------- K1: per-row stats of A (moc, dp) + X column-sum partials ----------------
__global__ __launch_bounds__(256) void k_rowstats(const float* __restrict__ A,
                                                  const float* __restrict__ X,
                                                  float* __restrict__ moc,
                                                  float* __restrict__ dpv,
                                                  float* __restrict__ Xpart)
{
    if (blockIdx.x < NB*CI*NN/4) {
        int wave = threadIdx.x >> 6, lane = threadIdx.x & 63;
        int row = blockIdx.x * 4 + wave;
        int i = row & (NN - 1);
        const float* rp = A + (size_t)row * NN;
        f32x4 v0 = *(const f32x4*)(rp + lane * 16);
        f32x4 v1 = *(const f32x4*)(rp + lane * 16 + 4);
        f32x4 v2 = *(const f32x4*)(rp + lane * 16 + 8);
        f32x4 v3 = *(const f32x4*)(rp + lane * 16 + 12);
        float s = 0.f;
        #pragma unroll
        for (int e = 0; e < 4; e++) s += v0[e] + v1[e] + v2[e] + v3[e];
        #pragma unroll
        for (int off = 32; off; off >>= 1) s += __shfl_down(s, off);
        if (lane == 0) {
            moc[row] = s * (1.f / NN);
            dpv[row] = rp[i];
        }
    } else {
        int idx = blockIdx.x - NB*CI*NN/4;
        int b = idx >> 4, seg = idx & 15;
        int g = threadIdx.x >> 6, x = threadIdx.x & 63;
        __shared__ float red[4][64];
        float s = 0.f;
        #pragma unroll
        for (int k = 0; k < 16; k++) {
            int i = seg*64 + g*16 + k;
            s += X[((size_t)b*NN + i)*XD + x];
        }
        red[g][x] = s;
        __syncthreads();
        if (threadIdx.x < 64)
            Xpart[idx*64 + threadIdx.x] =
                red[0][threadIdx.x]+red[1][threadIdx.x]+red[2][threadIdx.x]+red[3][threadIdx.x];
    }
}

// ---------------- K2: per-batch constants ----------------
__global__ __launch_bounds__(256) void k_batchstats(
    const float* __restrict__ Xpart,
    const float* __restrict__ moc, const float* __restrict__ dpv,
    const float* __restrict__ AW2, const float* __restrict__ AW4, const float* __restrict__ AW7,
    const float* __restrict__ Abias,
    const float* __restrict__ X1W2, const float* __restrict__ X1W5, const float* __restrict__ X1W6,
    const float* __restrict__ X1b,
    const float* __restrict__ X2W2, const float* __restrict__ X2W5, const float* __restrict__ X2W6,
    const float* __restrict__ X2b,
    float* __restrict__ constA_o, float* __restrict__ cx1_o, float* __restrict__ cx2_o)
{
    int b = blockIdx.x, tid = threadIdx.x;
    __shared__ float sdp[8][32], smoc[8][32];
    __shared__ float mdp_s[8], mall_s[8], mx_s[64];
    {
        int c = tid >> 5, rr = tid & 31;
        float pd = 0.f, pm = 0.f;
        for (int i = rr; i < NN; i += 32) {
            pd += dpv[(b*CI + c)*NN + i];
            pm += moc[(b*CI + c)*NN + i];
        }
        sdp[c][rr] = pd; smoc[c][rr] = pm;
    }
    if (tid < 64) {
        float px = 0.f;
        #pragma unroll
        for (int s = 0; s < 16; s++) px += Xpart[(b*16 + s)*64 + tid];
        mx_s[tid] = px * (1.f/NN);
    }
    __syncthreads();
    if (tid < 8) {
        float sd = 0.f, sm = 0.f;
        for (int k = 0; k < 32; k++) { sd += sdp[tid][k]; sm += smoc[tid][k]; }
        mdp_s[tid] = sd * (1.f/NN); mall_s[tid] = sm * (1.f/NN);
    }
    __syncthreads();
    if (tid < SO) {
        float v = Abias[tid];
        #pragma unroll
        for (int c = 0; c < 8; c++)
            v += mall_s[c]*AW2[c*SO+tid] + mdp_s[c]*AW4[c*SO+tid];
        for (int x = 0; x < 64; x++) v += mx_s[x]*AW7[x*SO+tid];
        constA_o[b*SO + tid] = v;
    }
    if (tid < 64) {
        float v1 = X1b[tid], v2 = X2b[tid];
        for (int x = 0; x < 64; x++) {
            float m = mx_s[x];
            v1 += m*X1W2[x*64+tid];
            v2 += m*X2W2[x*64+tid];
        }
        #pragma unroll
        for (int c = 0; c < 8; c++) {
            v1 += mall_s[c]*X1W6[c*64+tid] + mdp_s[c]*X1W5[c*64+tid];
            v2 += mall_s[c]*X2W6[c*64+tid] + mdp_s[c]*X2W5[c*64+tid];
        }
        cx1_o[b*64+tid] = v1; cx2_o[b*64+tid] = v2;
    }
}

// ---------------- K3: per-node row quantities: pairA, X1t, X2t^T ----------------
__global__ __launch_bounds__(256) void k_rows(const float* __restrict__ X,
    const float* __restrict__ moc, const float* __restrict__ dpv,
    const float* __restrict__ AW3, const float* __restrict__ AW5, const float* __restrict__ AW6,
    const float* __restrict__ X1W1, const float* __restrict__ X1W3, const float* __restrict__ X1W4,
    const float* __restrict__ X2W1, const float* __restrict__ X2W3, const float* __restrict__ X2W4,
    const float* __restrict__ cx1, const float* __restrict__ cx2,
    float* __restrict__ X1t, u16* __restrict__ X2tT,
    float* __restrict__ pairA, float* __restrict__ pairAT)
{
    int wave = threadIdx.x >> 6, u = threadIdx.x & 63;
    int r = blockIdx.x * 4 + wave;
    int b = r >> 10, i = r & (NN - 1);
    float xv = X[(size_t)r*XD + u];
    float a1 = cx1[b*XD + u], a2 = cx2[b*XD + u];
    int s = u & 15;
    float pa = 0.f;
    for (int x = 0; x < XD; x++) {
        float xx = __shfl(xv, x);
        a1 += xx * X1W1[x*XD + u];
        a2 += xx * X2W1[x*XD + u];
        pa += xx * AW6[x*SO + s];
    }
    #pragma unroll
    for (int c = 0; c < CI; c++) {
        float mv = moc[(b*CI + c)*NN + i];
        float dv = dpv[(b*CI + c)*NN + i];
        a1 += mv*X1W3[c*XD+u] + dv*X1W4[c*XD+u];
        a2 += mv*X2W3[c*XD+u] + dv*X2W4[c*XD+u];
        pa += mv*AW3[c*SO+s] + dv*AW5[c*SO+s];
    }
    X1t[(size_t)r*XD + u] = a1;
    X2tT[((size_t)b*XD + u)*NN + i] = f2bf(a2);
    if (u < SO) {
        pairA[(size_t)r*SO + u] = pa;
        pairAT[((size_t)b*SO + u)*NN + i] = pa;
    }
}

// ---------------- K4a: H + s2 ----------------
__global__ __launch_bounds__(256) void k_H(const float* __restrict__ pairAT,
                                           const u16* __restrict__ X2tT,
                                           float* __restrict__ H, float* __restrict__ s2)
{
    __shared__ float red[4][64];
    int tid = threadIdx.x;
    int t = tid & 63, g = tid >> 6;
    if (blockIdx.x < 64) {
        int b = blockIdx.x >> 4, s = blockIdx.x & 15;
        const u16* x2 = X2tT + ((size_t)(b*XD) + t)*NN;
        const float* par = pairAT + ((size_t)(b*SO) + s)*NN;
        float h = 0.f;
        for (int i = g*256; i < (g+1)*256; i += 8) {
            bf16x8 v = __builtin_bit_cast(bf16x8, *(const uint4*)(x2 + i));
            f32x4 p0 = *(const f32x4*)(par + i);
            f32x4 p1 = *(const f32x4*)(par + i + 4);
            #pragma unroll
            for (int e = 0; e < 4; e++)
                h += p0[e]*bf2f((u16)v[e]) + p1[e]*bf2f((u16)v[e+4]);
        }
        red[g][t] = h;
        __syncthreads();
        if (tid < 64)
            H[((size_t)(b*SO) + s)*64 + tid] = red[0][tid]+red[1][tid]+red[2][tid]+red[3][tid];
    } else {
        int b = blockIdx.x - 64;
        const u16* x2 = X2tT + ((size_t)(b*XD) + t)*NN;
        float p = 0.f;
        for (int i = g*256; i < (g+1)*256; i += 8) {
            bf16x8 v = __builtin_bit_cast(bf16x8, *(const uint4*)(x2 + i));
            #pragma unroll
            for (int e = 0; e < 8; e++) p += bf2f((u16)v[e]);
        }
        red[g][t] = p;
        __syncthreads();
        if (tid < 64)
            s2[b*64 + tid] = red[0][tid]+red[1][tid]+red[2][tid]+red[3][tid];
    }
}

// ---------------- K4b: K1, C2 + fused weights WGT ----------------
__global__ __launch_bounds__(256) void k_small2(const float* __restrict__ Wo, const float* __restrict__ AW1,
    const float* __restrict__ constA, const float* __restrict__ H, const float* __restrict__ s2,
    float* __restrict__ K1, float* __restrict__ C2, u16* __restrict__ WGT)
{
    int tid = threadIdx.x;
    if (blockIdx.x < 4) {
        int b = blockIdx.x;
        __shared__ float ls[4][64];
        int t = tid & 63, g = tid >> 6;
        const float* s2b = s2 + b*64;
        float pc = 0.f;
        #pragma unroll
        for (int si = 0; si < 4; si++) {
            int s = g*4 + si;
            float ca = constA[b*SO + s];
            const float* Hs = H + ((size_t)(b*SO) + s)*64;
            float v = 0.f;
            for (int tt = 0; tt < 64; tt++) {
                float w = Wo[(s*64+tt)*64 + t];
                v  += s2b[tt] * w;
                pc += (Hs[tt] + ca*s2b[tt]) * w;
            }
            K1[((size_t)(b*SO) + s)*XD + t] = v;
        }
        ls[g][t] = pc;
        __syncthreads();
        if (tid < 64) C2[b*XD + tid] = (ls[0][tid]+ls[1][tid]+ls[2][tid]+ls[3][tid]) * (1.f/NN);
    } else {
        int o = (blockIdx.x - 4)*256 + tid;
        int u = o >> 9;
        int k = o & 511;
        int c = k >> 6, t = k & 63;
        float v = 0.f;
        #pragma unroll
        for (int s = 0; s < SO; s++) v += AW1[c*SO+s] * Wo[(s*64+t)*64 + u];
        WGT[(size_t)u*512 + k] = f2bf(v);
    }
}

// ---------------- K5: fused At + G + out1, LDS-staged A, coalesced everywhere ----------------
// Grid: 256 blocks = (b, 16-row i-tile). 512 threads = 8 waves, 1 block/CU.
// Per 64-column chunk (16 chunks):
//   stage A[8c][16i][64j] f32 (32 KB) + X2[64t][64j] bf16 (8 KB) into LDS via
//   coalesced reg-staged loads (issued one chunk early) + XOR-swizzled ds_write.
//   G phase: wave = channel c; acc[nt] accumulates over ALL j (no cross-wave reduce).
//   At phase: wave owns 2 i-rows; lanes span the 64 contiguous j; stores 256B-coalesced.
// After the loop, acc -> bf16 Gb tile (unions with the A-stage buffer) -> out1 epilogue.
__global__ __launch_bounds__(512, 2) void k_fused(
    const float* __restrict__ A, const u16* __restrict__ X2tT,
    const float* __restrict__ AW1,
    const float* __restrict__ pairA, const float* __restrict__ pairAT,
    const float* __restrict__ constA,
    const u16* __restrict__ WGT, const float* __restrict__ K1,
    const float* __restrict__ C2, const float* __restrict__ X1t,
    const float* __restrict__ outb,
    float* __restrict__ out0, float* __restrict__ out1)
{
    // union: A-stage f32[128 rows][64j] (row stride 256 B, XOR-swizzled) = 32 KB
    //        | Gb u16[16][520] = 16.6 KB (used only after the chunk loop)
    __shared__ __align__(16) char smem[32768];
    __shared__ __align__(16) u16 X2s[64][64];     // 8 KB, XOR-swizzled rows of 128 B
    __shared__ __align__(16) float W1s[CI][SO];

    int tid = threadIdx.x;
    int wave = tid >> 6, lane = tid & 63;
    int lr = lane & 15, lq = lane >> 4;
    int b = blockIdx.x >> 6;
    int i0 = (blockIdx.x & 63) * 16;

    if (tid < CI*SO) W1s[tid >> 4][tid & 15] = AW1[tid];

    // per-wave constants: rc[i2][s] = pairA[i,s] + constA[s] for this wave's 2 i-rows
    int iA = wave*2, iB = wave*2 + 1;
    float rcA[SO], rcB[SO];
    #pragma unroll
    for (int s = 0; s < SO; s++) {
        float ca = constA[b*SO + s];
        rcA[s] = pairA[((size_t)(b*NN) + i0 + iA)*SO + s] + ca;
        rcB[s] = pairA[((size_t)(b*NN) + i0 + iB)*SO + s] + ca;
    }

    f32x4 acc[4];
    #pragma unroll
    for (int nt = 0; nt < 4; nt++) acc[nt] = (f32x4){0.f,0.f,0.f,0.f};

    // staging registers (issue-early / write-late)
    uint4 rA0, rA1, rA2, rA3, rX;

#define STAGE_LOAD(CH) { \
    int jb = (CH)*64; \
    int rr0 = (wave*4 + 0)*4 + (lane>>4); \
    int rr1 = (wave*4 + 1)*4 + (lane>>4); \
    int rr2 = (wave*4 + 2)*4 + (lane>>4); \
    int rr3 = (wave*4 + 3)*4 + (lane>>4); \
    rA0 = *(const uint4*)(A + (((size_t)(b*CI + (rr0>>4)))*NN + i0 + (rr0&15))*NN + jb + (lane&15)*4); \
    rA1 = *(const uint4*)(A + (((size_t)(b*CI + (rr1>>4)))*NN + i0 + (rr1&15))*NN + jb + (lane&15)*4); \
    rA2 = *(const uint4*)(A + (((size_t)(b*CI + (rr2>>4)))*NN + i0 + (rr2&15))*NN + jb + (lane&15)*4); \
    rA3 = *(const uint4*)(A + (((size_t)(b*CI + (rr3>>4)))*NN + i0 + (rr3&15))*NN + jb + (lane&15)*4); \
    int tt = wave*8 + (lane>>3); \
    rX = *(const uint4*)(X2tT + ((size_t)(b*XD) + tt)*NN + jb + (lane&7)*8); \
}

#define STAGE_WRITE() { \
    int rr0 = (wave*4 + 0)*4 + (lane>>4); \
    int rr1 = (wave*4 + 1)*4 + (lane>>4); \
    int rr2 = (wave*4 + 2)*4 + (lane>>4); \
    int rr3 = (wave*4 + 3)*4 + (lane>>4); \
    *(uint4*)(smem + rr0*256 + (((lane&15)*16) ^ ((rr0&7)<<4))) = rA0; \
    *(uint4*)(smem + rr1*256 + (((lane&15)*16) ^ ((rr1&7)<<4))) = rA1; \
    *(uint4*)(smem + rr2*256 + (((lane&15)*16) ^ ((rr2&7)<<4))) = rA2; \
    *(uint4*)(smem + rr3*256 + (((lane&15)*16) ^ ((rr3&7)<<4))) = rA3; \
    int tt = wave*8 + (lane>>3); \
    *(uint4*)((char*)X2s + tt*128 + (((lane&7)*16) ^ ((tt&7)<<4))) = rX; \
}

    STAGE_LOAD(0);

    for (int ch = 0; ch < 16; ch++) {
        __syncthreads();            // LDS free (previous chunk's compute done / W1s staged)
        STAGE_WRITE();
        __syncthreads();            // staged data visible
        if (ch < 15) STAGE_LOAD(ch + 1);   // prefetch next chunk under this chunk's compute

        int j0v = ch * 64;

        // ---- G phase: wave = channel, 2 k-steps of 32, 4 t-quarters ----
        {
            int rr = wave*16 + lr;
            int swz = (lr & 7) << 4;
            #pragma unroll
            for (int ks = 0; ks < 2; ks++) {
                int y0 = ks*128 + lq*32;
                f32x4 A0 = __builtin_bit_cast(f32x4, *(const uint4*)(smem + rr*256 + (y0 ^ swz)));
                f32x4 A1 = __builtin_bit_cast(f32x4, *(const uint4*)(smem + rr*256 + ((y0 + 16) ^ swz)));
                bf16x8 af;
                #pragma unroll
                for (int e = 0; e < 4; e++) { af[e] = (short)f2bf(A0[e]); af[e+4] = (short)f2bf(A1[e]); }
                #pragma unroll
                for (int nt = 0; nt < 4; nt++) {
                    int tt = nt*16 + lr;
                    bf16x8 bfr = __builtin_bit_cast(bf16x8,
                        *(const uint4*)((char*)X2s + tt*128 + ((ks*64 + lq*16) ^ ((tt&7)<<4))));
                    acc[nt] = __builtin_amdgcn_mfma_f32_16x16x32_bf16(af, bfr, acc[nt], 0, 0, 0);
                }
            }
        }

        // ---- At phase: this wave's 2 i-rows, lanes span the 64 j of this chunk ----
        {
            float o0[SO], o1[SO];
            #pragma unroll
            for (int s = 0; s < SO; s++) { o0[s] = 0.f; o1[s] = 0.f; }
            for (int c = 0; c < CI; c++) {
                f32x4 w0 = *(const f32x4*)&W1s[c][0];
                f32x4 w1 = *(const f32x4*)&W1s[c][4];
                f32x4 w2 = *(const f32x4*)&W1s[c][8];
                f32x4 w3 = *(const f32x4*)&W1s[c][12];
                float W1v[SO];
                #pragma unroll
                for (int e = 0; e < 4; e++) { W1v[e] = w0[e]; W1v[4+e] = w1[e]; W1v[8+e] = w2[e]; W1v[12+e] = w3[e]; }
                int ra = c*16 + iA, rb = c*16 + iB;
                float aA = *(const float*)(smem + ra*256 + ((lane*4) ^ ((ra&7)<<4)));
                float aB = *(const float*)(smem + rb*256 + ((lane*4) ^ ((rb&7)<<4)));
                #pragma unroll
                for (int s = 0; s < SO; s++) {
                    o0[s] = fmaf(aA, W1v[s], o0[s]);
                    o1[s] = fmaf(aB, W1v[s], o1[s]);
                }
            }
            #pragma unroll
            for (int s = 0; s < SO; s++) {
                float pj = pairAT[((size_t)(b*SO) + s)*NN + j0v + lane];
                out0[((size_t)(b*SO + s)*NN + i0 + iA)*NN + j0v + lane] = o0[s] + rcA[s] + pj;
                out0[((size_t)(b*SO + s)*NN + i0 + iB)*NN + j0v + lane] = o1[s] + rcB[s] + pj;
            }
        }
    }

    // ---- G -> bf16 Gb tile (unions with the A-stage buffer) ----
    __syncthreads();                 // all chunk compute done; A-stage region dead
    u16* Gb = (u16*)smem;            // [16][520]
    #pragma unroll
    for (int nt = 0; nt < 4; nt++) {
        #pragma unroll
        for (int reg = 0; reg < 4; reg++)
            Gb[(lq*4 + reg)*520 + wave*64 + nt*16 + lr] = f2bf(acc[nt][reg]);
    }
    __syncthreads();

    // ---- out1 epilogue (waves 0-3; 16 rows x 64 u, K=512) ----
    if (wave < 4) {
        int nt = wave;
        f32x4 acc1 = (f32x4){0.f,0.f,0.f,0.f};
        #pragma unroll
        for (int k0 = 0; k0 < 512; k0 += 32) {
            bf16x8 ga = __builtin_bit_cast(bf16x8, *(const uint4*)&Gb[lr*520 + k0 + lq*8]);
            bf16x8 wb = __builtin_bit_cast(bf16x8,
                *(const uint4*)(WGT + (size_t)(nt*16 + lr)*512 + k0 + lq*8));
            acc1 = __builtin_amdgcn_mfma_f32_16x16x32_bf16(ga, wb, acc1, 0, 0, 0);
        }
        int u = nt*16 + lr;
        float k1c[SO];
        #pragma unroll
        for (int s = 0; s < SO; s++) k1c[s] = K1[((size_t)(b*SO) + s)*XD + u];
        float cb = C2[b*XD + u] + outb[u];
        #pragma unroll
        for (int reg = 0; reg < 4; reg++) {
            int ii = i0 + lq*4 + reg;
            const float* pa = pairA + ((size_t)(b*NN) + ii)*SO;
            float s16 = 0.f;
            #pragma unroll
            for (int s = 0; s < SO; s++) s16 += pa[s] * k1c[s];
            out1[((size_t)(b*NN) + ii)*XD + u] =
                (acc1[reg] + s16) * (1.f/NN) + cb
                + X1t[((size_t)(b*NN) + ii)*XD + u];
        }
    }
#undef STAGE_LOAD
#undef STAGE_WRITE
}

extern "C" void kernel_launch(void* const* d_in, const int* in_sizes, int n_in,
                              void* d_out, int out_size, void* d_ws, size_t ws_size,
                              hipStream_t stream)
{
    const float* A     = (const float*)d_in[0];
    const float* X     = (const float*)d_in[1];
    const float* AW1   = (const float*)d_in[2];
    const float* AW2   = (const float*)d_in[3];
    const float* AW3   = (const float*)d_in[4];
    const float* AW4   = (const float*)d_in[5];
    const float* AW5   = (const float*)d_in[6];
    const float* AW6   = (const float*)d_in[7];
    const float* AW7   = (const float*)d_in[8];
    const float* Abias = (const float*)d_in[9];
    const float* X1W1  = (const float*)d_in[10];
    const float* X1W2  = (const float*)d_in[11];
    const float* X1W3  = (const float*)d_in[12];
    const float* X1W4  = (const float*)d_in[13];
    const float* X1W5  = (const float*)d_in[14];
    const float* X1W6  = (const float*)d_in[15];
    const float* X1b   = (const float*)d_in[16];
    const float* X2W1  = (const float*)d_in[17];
    const float* X2W2  = (const float*)d_in[18];
    const float* X2W3  = (const float*)d_in[19];
    const float* X2W4  = (const float*)d_in[20];
    const float* X2W5  = (const float*)d_in[21];
    const float* X2W6  = (const float*)d_in[22];
    const float* X2b   = (const float*)d_in[23];
    const float* Wo    = (const float*)d_in[24];
    const float* outb  = (const float*)d_in[25];

    char* ws = (char*)d_ws;
    float* moc    = (float*)(ws + WS_MOC);
    float* dpv    = (float*)(ws + WS_DP);
    float* constA = (float*)(ws + WS_CONSTA);
    float* cx1    = (float*)(ws + WS_CX1);
    float* cx2    = (float*)(ws + WS_CX2);
    float* K1     = (float*)(ws + WS_K1);
    float* C2     = (float*)(ws + WS_C2);
    float* pairA  = (float*)(ws + WS_PAIRA);
    float* pairAT = (float*)(ws + WS_PAIRAT);
    float* X1t    = (float*)(ws + WS_X1T);
    u16*   X2tT   = (u16*)(ws + WS_X2TT);
    u16*   WGT    = (u16*)(ws + WS_WGT);
    float* H      = (float*)(ws + WS_H);
    float* Xpart  = (float*)(ws + WS_XPART);
    float* s2     = (float*)(ws + WS_S2);

    float* out0 = (float*)d_out;
    float* out1 = out0 + (size_t)NB*SO*NN*NN;

    k_rowstats<<<dim3(NB*CI*NN/4 + 64), dim3(256), 0, stream>>>(A, X, moc, dpv, Xpart);
    k_batchstats<<<dim3(NB), dim3(256), 0, stream>>>(Xpart, moc, dpv,
        AW2, AW4, AW7, Abias, X1W2, X1W5, X1W6, X1b, X2W2, X2W5, X2W6, X2b,
        constA, cx1, cx2);
    k_rows<<<dim3(NB*NN/4), dim3(256), 0, stream>>>(X, moc, dpv,
        AW3, AW5, AW6, X1W1, X1W3, X1W4, X2W1, X2W3, X2W4, cx1, cx2,
        X1t, X2tT, pairA, pairAT);
    k_H<<<dim3(68), dim3(256), 0, stream>>>(pairAT, X2tT, H, s2);
    k_small2<<<dim3(132), dim3(256), 0, stream>>>(Wo, AW1, constA, H, s2, K1, C2, WGT);
    k_fused<<<dim3(NB*NN/16), dim3(512), 0, stream>>>(A, X2tT, AW1,
        pairA, pairAT, constA, WGT, K1, C2, X1t, outb, out0, out1);
}